// Round 7
// baseline (271.869 us; speedup 1.0000x reference)
//
#include <hip/hip_runtime.h>
#include <hip/hip_bf16.h>
#include <math.h>

#define HW 16384

__device__ __forceinline__ float LD(const void* p, long i, int bf){
  return bf ? __bfloat162float(((const __hip_bfloat16*)p)[i]) : ((const float*)p)[i];
}
__device__ __forceinline__ float geluf(float x){ return 0.5f*x*(1.0f + erff(x*0.70710678118654752f)); }
__device__ __forceinline__ int rev7(int i){ return (int)(__brev((unsigned)i)>>25); }

__device__ __forceinline__ void fft128(float* Ar, float* Ai, const float* ct, const float* st,
                                       int lane, float dir){
  #pragma unroll
  for(int len=2; len<=128; len<<=1){
    int half=len>>1;
    int pos = lane & (half-1);
    int i1 = ((lane & ~(half-1))<<1) | pos;
    int i2 = i1 + half;
    int tw = pos * (128/len);
    float wr = ct[tw], wi = dir*st[tw];
    float xr=Ar[i2], xi=Ai[i2];
    float tr = xr*wr - xi*wi;
    float ti = xr*wi + xi*wr;
    float ur=Ar[i1], ui=Ai[i1];
    Ar[i1]=ur+tr; Ai[i1]=ui+ti;
    Ar[i2]=ur-tr; Ai[i2]=ui-ti;
  }
}

#define MAKE_TWP(ct,st) { int tt=threadIdx.x; if(tt<128){ float ang=6.283185307179586f*(float)tt/128.f; float s_,c_; sincosf(ang,&s_,&c_); (ct)[tt]=c_; (st)[tt]=s_; } }

// ---- ws layout (float offsets) ----
#define OFF_M    0
#define OFF_G    3072
#define OFF_MB   6144
#define OFF_FLAG 10240
#define OFF_QDIM 16384
#define OFF_KDIM (16384 + 1048576)
#define OFF_VDIM (16384 + 2*1048576)
#define OFF_QMIX (16384 + 3*1048576)
#define OFF_KMIX (16384 + 4*1048576)
#define OFF_S    (16384 + 5*1048576)
#define FSZ 532480            // 4*128*65*16
// FA..FE = OFF_S..+5*FSZ ; M96 = FE+FSZ (1.5M) ; G96 overlays dead qd/kd @OFF_QDIM

// ---- shared wave_dw body: m96 -> g96, o in [0, 1572864) ----
__device__ __forceinline__ void wave_dw_body(int o, const float* m96, float* g96, const float* wdw){
  int ch = o%96; int r = o/96; int px = r&4095; int b = r>>12;
  int i = px>>6, j = px&63;
  long mb = (long)b*393216;
  float acc=0.f;
  for(int dp=0;dp<3;dp++){ int ii=i-1+dp; if(ii<0||ii>=64) continue;
    for(int dq=0;dq<3;dq++){ int jj=j-1+dq; if(jj<0||jj>=64) continue;
      acc += wdw[ch*9+dp*3+dq]*m96[mb + (long)(ii*64+jj)*96 + ch]; } }
  g96[o]=geluf(acc);
}

// K0: fold (48 blocks) + flag/zero (block 48)
// M stored as ws[cc*48 + mat*16 + rr]   ([c][48] layout for k_dims v3)
__global__ void k_head(const void* Wq, const void* Wk, const void* Wv,
                       const void* Wr, const void* bng, float* ws){
  __shared__ float wr[8192];
  __shared__ float part[256];
  int blk=blockIdx.x, t=threadIdx.x;
  if(blk==48){
    for(int i=3072+t;i<10240;i+=256) ws[i]=0.f;
    if(t==0){
      float v = ((const float*)bng)[0];
      ((int*)ws)[OFF_FLAG] = (v==1.0f) ? 0 : 1;
    }
    return;
  }
  int bf = (((const float*)bng)[0]==1.0f) ? 0 : 1;
  int mat=blk>>4, seg=blk&15;
  const void* Wsrc = mat==0 ? Wq : (mat==1 ? Wk : Wv);
  for(int i=t;i<8192;i+=256) wr[i]=LD(Wr,i,bf);
  __syncthreads();
  int o=t&63, jseg=t>>6;
  int c=seg*4+(o>>4), r=o&15;
  float acc=0.f;
  for(int j=jseg*128;j<jseg*128+128;j++) acc += LD(Wsrc,(long)c*512+j,bf)*wr[j*16+r];
  part[jseg*64+o]=acc;
  __syncthreads();
  if(t<64){
    float s=part[t]+part[64+t]+part[128+t]+part[192+t];
    int cc=seg*4+(t>>4), rr=t&15;
    ws[cc*48 + mat*16 + rr]=s;   // [c][48] layout
  }
}

// K1 v3: q/k/v_dim = x @ M. LDS register-tiled GEMM.
__global__ void k_dims(const void* x, const float* ws,
                       float* qd, float* kd, float* vd, const int* flg){
  int bf=*flg;
  __shared__ __align__(16) float ms[3072];       // [c][48]
  __shared__ __align__(16) float xs[64*130];     // [c][px], stride 130
  int t=threadIdx.x;
  int b = blockIdx.x>>7;
  int pix0 = (blockIdx.x&127)<<7;
  for(int i=t;i<3072;i+=256) ms[i]=ws[i];
  long base = ((long)b*HW + pix0)*64;
  if(!bf){
    const float4* xp = (const float4*)((const float*)x + base);
    for(int e=t;e<2048;e+=256){
      int px=e>>4, c4=(e&15)<<2;
      float4 v = xp[e];
      xs[(c4  )*130+px]=v.x; xs[(c4+1)*130+px]=v.y;
      xs[(c4+2)*130+px]=v.z; xs[(c4+3)*130+px]=v.w;
    }
  } else {
    const uint4* xp = (const uint4*)((const __hip_bfloat16*)x + base);
    for(int e=t;e<1024;e+=256){
      int px=e>>3, c8=(e&7)<<3;
      uint4 u = xp[e];
      unsigned uu[4]={u.x,u.y,u.z,u.w};
      #pragma unroll
      for(int q=0;q<4;q++){
        xs[(c8+2*q  )*130+px] = __uint_as_float((uu[q]&0xffffu)<<16);
        xs[(c8+2*q+1)*130+px] = __uint_as_float(uu[q]&0xffff0000u);
      }
    }
  }
  __syncthreads();
  int pxg=t>>2, rg=t&3;
  int px0=pxg<<1, r0=rg*12;
  float acc0[12], acc1[12];
  #pragma unroll
  for(int j=0;j<12;j++){ acc0[j]=0.f; acc1[j]=0.f; }
  #pragma unroll 4
  for(int c=0;c<64;c++){
    float2 xv = *(const float2*)&xs[c*130+px0];
    const float4* mp = (const float4*)&ms[c*48+r0];
    float4 m0=mp[0], m1=mp[1], m2=mp[2];
    acc0[0]+=xv.x*m0.x; acc0[1]+=xv.x*m0.y; acc0[2]+=xv.x*m0.z; acc0[3]+=xv.x*m0.w;
    acc0[4]+=xv.x*m1.x; acc0[5]+=xv.x*m1.y; acc0[6]+=xv.x*m1.z; acc0[7]+=xv.x*m1.w;
    acc0[8]+=xv.x*m2.x; acc0[9]+=xv.x*m2.y; acc0[10]+=xv.x*m2.z; acc0[11]+=xv.x*m2.w;
    acc1[0]+=xv.y*m0.x; acc1[1]+=xv.y*m0.y; acc1[2]+=xv.y*m0.z; acc1[3]+=xv.y*m0.w;
    acc1[4]+=xv.y*m1.x; acc1[5]+=xv.y*m1.y; acc1[6]+=xv.y*m1.z; acc1[7]+=xv.y*m1.w;
    acc1[8]+=xv.y*m2.x; acc1[9]+=xv.y*m2.y; acc1[10]+=xv.y*m2.z; acc1[11]+=xv.y*m2.w;
  }
  __syncthreads();     // xs reads done -> overlay with sh[128][49]
  float* sh = xs;
  #pragma unroll
  for(int j=0;j<12;j++){
    sh[(px0  )*49 + r0+j] = acc0[j];
    sh[(px0+1)*49 + r0+j] = acc1[j];
  }
  __syncthreads();
  long ob = ((long)b*HW + pix0)*16;
  for(int e=t;e<2048;e+=256){
    int px=e>>4, rr=e&15;
    qd[ob+e]=sh[px*49 + rr];
    kd[ob+e]=sh[px*49 + 16 + rr];
    vd[ob+e]=sh[px*49 + 32 + rr];
  }
}

// K2 merged: [0,256) spatial (2 rows/blk, f2-vectorized) | [256,512) fft_row | [512,1024) wave_a v3
__global__ void k_mix3(const float* qd, float* qm, const void* dw, const void* pw, const void* gamma,
                       const float* kd, float* Rre, float* Rim,
                       const float* vd, float* m96, const void* win, const void* bng, const void* bnb,
                       const int* flg){
  __shared__ __align__(16) float smem[9664];
  int bf=*flg;
  int blk=blockIdx.x, t=threadIdx.x;
  if(blk<256){
    // ---- SpitialUnit, 2 y-rows per block, float2 channel-vectorized ----
    float* tile=smem;                 // [4*128][18] = 9216
    float* dws=smem+9216;             // [tap][16] = 144
    float* pws=smem+9360;             // [c][16]  = 256
    float* gsm=smem+9616;             // 16
    int b=blk>>6, y0=(blk&63)<<1;
    for(int i=t;i<144;i+=256){ int tap=i>>4, ch=i&15; dws[i]=LD(dw,ch*9+tap,bf); }
    if(t<256) pws[t]=LD(pw,t,bf);
    if(t<16) gsm[t]=LD(gamma,t,bf);
    for(int i=t;i<8192;i+=256){
      int ry=i>>11, rem=i&2047, xx=rem>>4, ch=rem&15;
      int yy=y0-1+ry;
      tile[(ry*128+xx)*18+ch] = (yy>=0&&yy<128) ? qd[(long)(b*128+yy)*2048 + rem] : 0.f;
    }
    __syncthreads();
    int ty=t>>7, x=t&127;
    float2 g2[8];
    #pragma unroll
    for(int k=0;k<8;k++){ g2[k].x=0.f; g2[k].y=0.f; }
    for(int p=0;p<3;p++){
      int row=ty+p;
      for(int q=0;q<3;q++){
        int xx=x-1+q;
        if(xx<0||xx>=128) continue;
        const float2* tv=(const float2*)&tile[(row*128+xx)*18];
        const float2* wv=(const float2*)&dws[(p*3+q)*16];
        #pragma unroll
        for(int k=0;k<8;k++){
          float2 tt=tv[k], ww=wv[k];
          g2[k].x += ww.x*tt.x; g2[k].y += ww.y*tt.y;
        }
      }
    }
    float ge[16];
    #pragma unroll
    for(int k=0;k<8;k++){ ge[2*k]=geluf(g2[k].x); ge[2*k+1]=geluf(g2[k].y); }
    long ob = ((long)(b*128+y0+ty)*128 + x)*16;
    for(int c=0;c<16;c++){
      const float2* pv=(const float2*)&pws[c*16];
      float acc=0.f;
      #pragma unroll
      for(int k=0;k<8;k++){ float2 pp=pv[k]; acc += pp.x*ge[2*k]+pp.y*ge[2*k+1]; }
      qm[ob+c] = tile[((1+ty)*128+x)*18+c] + gsm[c]*acc;
    }
  } else if(blk<512){
    // ---- row rfft: kd NHWC -> R[b][y][v][c] ----
    float* slab=smem; float* outre=smem+4160; float* outim=smem+6272;
    float* Ar=smem+8384; float* Ai=smem+8896; float* ct=smem+9408; float* st=smem+9536;
    int blk2=blk-256;
    int b=blk2>>6, y0=(blk2&63)<<1;
    MAKE_TWP(ct,st);
    long gbase = ((long)(b*128+y0))*2048;
    for(int e=t;e<4096;e+=256){
      int yl=e>>11, rem=e&2047, x=rem>>4, c=rem&15;
      slab[yl*2080 + c*130 + x] = kd[gbase + e];
    }
    __syncthreads();
    int w=t>>6, l=t&63, wb=w<<7;
    for(int li=w; li<32; li+=4){
      int yl=li>>4, c=li&15;
      int sb = yl*2080 + c*130;
      float v0=slab[sb+l], v1=slab[sb+64+l];
      int r0=rev7(l), r1=rev7(64+l);
      Ar[wb+r0]=v0; Ai[wb+r0]=0.f;
      Ar[wb+r1]=v1; Ai[wb+r1]=0.f;
      fft128(Ar+wb, Ai+wb, ct, st, l, -1.f);
      int ob = yl*1056 + c*66;
      outre[ob+l]=Ar[wb+l]; outim[ob+l]=Ai[wb+l];
      if(l==0){ outre[ob+64]=Ar[wb+64]; outim[ob+64]=Ai[wb+64]; }
    }
    __syncthreads();
    long obase = ((long)(b*128+y0))*1040;
    for(int e=t;e<2080;e+=256){
      int yl=e/1040, rem=e%1040, v=rem>>4, c=rem&15;
      Rre[obase+e]=outre[yl*1056 + c*66 + v];
      Rim[obase+e]=outim[yl*1056 + c*66 + v];
    }
  } else {
    // ---- wave_a v3: haar + BN + mlp_in (48->96) -> m96, register-tiled GEMM ----
    float* wiT=smem;                  // [cc][96] stride 100 = 4800
    float* vds=smem+4800;             // 2048 (2 rows x 64 px x 16)
    float* ns =smem+6848;             // [32 hp][48] stride 49 = 1568
    float* gsm=smem+8416;             // 48
    float* bsm=smem+8464;             // 48
    int blk3=blk-512;                 // [0,512)
    int b = blk3>>7;
    int hpbase = (blk3&127)<<5;       // 32 hp per block (half row of j)
    int i0 = hpbase>>6, j0 = hpbase&63;
    for(int i=t;i<4608;i+=256){ int ch=i/48, cc=i-ch*48; wiT[cc*100+ch]=LD(win,i,bf); }
    if(t<48){ gsm[t]=LD(bng,t,bf)*(1.f/sqrtf(1.f+1e-5f)); bsm[t]=LD(bnb,t,bf); }
    long rb0 = ((long)(b*128 + 2*i0)*128 + 2*j0)*16;
    {
      const float4* v4a=(const float4*)(vd+rb0);
      const float4* v4b=(const float4*)(vd+rb0+2048);
      ((float4*)vds)[t] = v4a[t];
      ((float4*)(vds+1024))[t] = v4b[t];
    }
    __syncthreads();
    for(int o=t;o<1536;o+=256){
      int p=o/48, cc=o-p*48;
      int m=cc+16, c=m>>2, f=m&3;
      float a =vds[(2*p)*16+c],      bv=vds[(2*p+1)*16+c];
      float cv=vds[1024+(2*p)*16+c], dvv=vds[1024+(2*p+1)*16+c];
      float v;
      if(f==0)      v=(a+bv+cv+dvv);
      else if(f==1) v=(a-bv+cv-dvv);
      else if(f==2) v=(a+bv-cv-dvv);
      else          v=(a-bv-cv+dvv);
      ns[p*49+cc] = v*0.5f*gsm[cc]+bsm[cc];
    }
    __syncthreads();
    int px=t>>3, chg=t&7;
    int ch0=chg*12;
    float4 a0={0,0,0,0}, a1={0,0,0,0}, a2={0,0,0,0};
    #pragma unroll 4
    for(int cc=0;cc<48;cc++){
      float nsv = ns[px*49+cc];
      const float4* wp = (const float4*)&wiT[cc*100+ch0];
      float4 w0=wp[0], w1=wp[1], w2=wp[2];
      a0.x+=nsv*w0.x; a0.y+=nsv*w0.y; a0.z+=nsv*w0.z; a0.w+=nsv*w0.w;
      a1.x+=nsv*w1.x; a1.y+=nsv*w1.y; a1.z+=nsv*w1.z; a1.w+=nsv*w1.w;
      a2.x+=nsv*w2.x; a2.y+=nsv*w2.y; a2.z+=nsv*w2.z; a2.w+=nsv*w2.w;
    }
    long ob = ((long)b*4096 + hpbase + px)*96 + ch0;
    float4* mp=(float4*)(m96+ob);
    mp[0]=a0; mp[1]=a1; mp[2]=a2;
  }
}

// F2+F3: [0,260) col fft over y, amp/phase, masked mix + gelu | [260,2308) wave_dw chunk 0
__global__ void k_fft_col(const float* Rre, const float* Rim,
                          float* glo, float* ghi, float* pho,
                          const void* alpw, const void* ahpw,
                          const void* phpw, const void* phs,
                          const float* m96, float* g96, const void* wdw_,
                          const int* flg){
  __shared__ float sre[2080], sim[2080];
  __shared__ float og[2080], oh[2080], op[2080];
  __shared__ float Ar[512], Ai[512];
  __shared__ float ct[128], st[128];
  __shared__ float wl[256], wh[256], wp[256];
  int t=threadIdx.x;
  int bf=*flg;
  int blk=blockIdx.x;
  if(blk>=260){
    float* wdw=sre;  // 864 fits
    for(int i=t;i<864;i+=256) wdw[i]=LD(wdw_,i,bf);
    __syncthreads();
    wave_dw_body((blk-260)*256+t, m96, g96, wdw);
    return;
  }
  int b = blk/65, v = blk%65;
  MAKE_TWP(ct,st);
  wl[t]=LD(alpw,t,bf); wh[t]=LD(ahpw,t,bf); wp[t]=LD(phpw,t,bf);
  long ibase = ((long)b*128)*1040 + v*16;
  for(int e=t;e<2048;e+=256){
    int y=e>>4, c=e&15;
    sre[c*130+y]=Rre[ibase + (long)y*1040 + c];
    sim[c*130+y]=Rim[ibase + (long)y*1040 + c];
  }
  __syncthreads();
  int w=t>>6, l=t&63, wb=w<<7;
  const float inv=1.f/128.f;
  for(int c=w; c<16; c+=4){
    int sb=c*130;
    float x0r=sre[sb+l], x0i=sim[sb+l], x1r=sre[sb+64+l], x1i=sim[sb+64+l];
    int r0=rev7(l), r1=rev7(64+l);
    Ar[wb+r0]=x0r; Ai[wb+r0]=x0i;
    Ar[wb+r1]=x1r; Ai[wb+r1]=x1i;
    fft128(Ar+wb, Ai+wb, ct, st, l, -1.f);
    float re0=Ar[wb+l]*inv, im0=Ai[wb+l]*inv;
    float re1=Ar[wb+64+l]*inv, im1=Ai[wb+64+l]*inv;
    sre[sb+l]=sqrtf(re0*re0+im0*im0); sim[sb+l]=atan2f(im0,re0);
    sre[sb+64+l]=sqrtf(re1*re1+im1*im1); sim[sb+64+l]=atan2f(im1,re1);
  }
  __syncthreads();
  {
    int u = t&127, half = t>>7;
    float yy=(float)u/127.f, xx=(float)v/64.f;
    float rr=sqrtf(yy*yy+xx*xx);
    float lo = 1.f/(1.f+expf((rr-0.25f)*20.f));
    float hi = 1.f-lo;
    float av[16], pv[16];
    for(int ch=0;ch<16;ch++){ av[ch]=sre[ch*130+u]; pv[ch]=sim[ch*130+u]; }
    float pscale = LD(phs,0,bf);
    for(int c=half*8;c<half*8+8;c++){
      float al=0.f, ah=0.f, pp=0.f;
      for(int ch=0;ch<16;ch++){
        float a=av[ch];
        al += wl[c*16+ch]*(a*lo);
        ah += wh[c*16+ch]*(a*hi);
        pp += wp[c*16+ch]*pv[ch];
      }
      og[c*130+u]=geluf(al); oh[c*130+u]=geluf(ah); op[c*130+u]=pv[c]+pscale*pp;
    }
  }
  __syncthreads();
  long obase = ((long)b*128)*1040 + v*16;
  for(int e=t;e<2048;e+=256){
    int u=e>>4, c=e&15;
    long o = obase + (long)u*1040 + c;
    glo[o]=og[c*130+u]; ghi[o]=oh[c*130+u]; pho[o]=op[c*130+u];
  }
}

// I1 fused v2: [0,260) dw(3x3 gather) + Y=amp*e^{i phase} + inverse col fft | [260,2308) wave_dw chunk 1
// LDS stays 22KB (no column staging) — the 18 L2-resident gathers hide under the filler waves.
__global__ void k_ifft_four(const float* glo, const float* ghi, const float* pho,
                            float* Zre, float* Zim,
                            const void* aldw, const void* ahdw,
                            const float* m96, float* g96, const void* wdw_,
                            const int* flg){
  __shared__ float sre[2080], sim[2080];
  __shared__ float Ar[512], Ai[512];
  __shared__ float ct[128], st[128];
  __shared__ float wl[144], wh[144];
  int t=threadIdx.x;
  int blk=blockIdx.x;
  int bf=*flg;
  if(blk>=260){
    float* wdw=sre;  // 864 fits
    for(int i=t;i<864;i+=256) wdw[i]=LD(wdw_,i,bf);
    __syncthreads();
    wave_dw_body((blk-260+2048)*256+t, m96, g96, wdw);
    return;
  }
  int b = blk/65, v = blk%65;
  MAKE_TWP(ct,st);
  if(t<144){ wl[t]=LD(aldw,t,bf); wh[t]=LD(ahdw,t,bf); }
  __syncthreads();
  // dw + Y -> sre/sim (col-major c*130+u)
  for(int e=t;e<2048;e+=256){
    int u=e>>4, c=e&15;
    float acc=0.f;
    for(int dp=0;dp<3;dp++){
      int uu=u-1+dp; if(uu<0||uu>=128) continue;
      for(int dq=0;dq<3;dq++){
        int vv=v-1+dq; if(vv<0||vv>=65) continue;
        long idx=(((long)(b*128+uu))*65+vv)*16+c;
        acc += wl[c*9+dp*3+dq]*glo[idx] + wh[c*9+dp*3+dq]*ghi[idx];
      }
    }
    long o=(((long)(b*128+u))*65+v)*16+c;
    float s_,c_; sincosf(pho[o],&s_,&c_);
    sre[c*130+u]=acc*c_; sim[c*130+u]=acc*s_;
  }
  __syncthreads();
  int w=t>>6, l=t&63, wb=w<<7;
  for(int c=w; c<16; c+=4){
    int sb=c*130;
    float x0r=sre[sb+l], x0i=sim[sb+l], x1r=sre[sb+64+l], x1i=sim[sb+64+l];
    int r0=rev7(l), r1=rev7(64+l);
    Ar[wb+r0]=x0r; Ai[wb+r0]=x0i;
    Ar[wb+r1]=x1r; Ai[wb+r1]=x1i;
    fft128(Ar+wb, Ai+wb, ct, st, l, +1.f);
    sre[sb+l]=Ar[wb+l]; sim[sb+l]=Ai[wb+l];
    sre[sb+64+l]=Ar[wb+64+l]; sim[sb+64+l]=Ai[wb+64+l];
  }
  __syncthreads();
  long ibase = ((long)b*128)*1040 + v*16;
  for(int e=t;e<2048;e+=256){
    int y=e>>4, c=e&15;
    Zre[ibase + (long)y*1040 + c]=sre[c*130+y];
    Zim[ibase + (long)y*1040 + c]=sim[c*130+y];
  }
}

// K3: [0,256) ifft_row + fused gram -> atomicAdd G | [256,2304) wave_dw chunk 2
__global__ void k_irow_gram(const float* Zre, const float* Zim, const float* qm,
                            float* G, const float* m96, float* g96, const void* wdw_,
                            const int* flg){
  __shared__ float smem[9664];
  int blk=blockIdx.x, t=threadIdx.x;
  if(blk>=256){
    int bf=*flg;
    float* wdw=smem;
    for(int i=t;i<864;i+=256) wdw[i]=LD(wdw_,i,bf);
    __syncthreads();
    wave_dw_body((blk-256+4096)*256+t, m96, g96, wdw);
    return;
  }
  float* szre=smem; float* szim=smem+2112; float* oslab=smem+4224;
  float* Ar=smem+8384; float* Ai=smem+8896; float* ct=smem+9408; float* st=smem+9536;
  int b = blk>>6, y0 = (blk&63)<<1;
  MAKE_TWP(ct,st);
  long ibase = ((long)(b*128+y0))*1040;
  for(int e=t;e<2080;e+=256){
    int yl=e/1040, rem=e%1040, v=rem>>4, c=rem&15;
    szre[yl*1056 + c*66 + v]=Zre[ibase+e];
    szim[yl*1056 + c*66 + v]=Zim[ibase+e];
  }
  __syncthreads();
  int w=t>>6, l=t&63, wb=w<<7;
  const float inv=1.f/128.f;
  for(int li=w; li<32; li+=4){
    int yl=li>>4, c=li&15;
    int sb = yl*1056 + c*66;
    float zr0 = szre[sb+l];
    float zi0 = (l==0)?0.f:szim[sb+l];
    float zr1, zi1;
    if(l==0){ zr1=szre[sb+64]; zi1=0.f; }
    else    { zr1=szre[sb+64-l]; zi1=-szim[sb+64-l]; }
    int r0=rev7(l), r1=rev7(64+l);
    Ar[wb+r0]=zr0; Ai[wb+r0]=zi0;
    Ar[wb+r1]=zr1; Ai[wb+r1]=zi1;
    fft128(Ar+wb, Ai+wb, ct, st, l, +1.f);
    int ob = yl*2080 + c*130;
    oslab[ob+l]=Ar[wb+l]*inv;
    oslab[ob+64+l]=Ar[wb+64+l]*inv;
  }
  __syncthreads();
  // ---- fused gram: km tile is in oslab; stage qm rows into szre region ----
  float* qs = smem;   // 4096 floats (overlays szre+szim, dead now)
  long qbase = ((long)(b*128+y0))*2048;
  for(int e=t;e<4096;e+=256) qs[e]=qm[qbase+e];
  __syncthreads();
  int r=t>>4, s=t&15;
  float akq=0.f, akk=0.f, aqq=0.f;
  for(int p=0;p<256;p++){
    int yl=p>>7, x=p&127;
    float kr = oslab[yl*2080 + r*130 + x];
    float ks_ = oslab[yl*2080 + s*130 + x];
    float qr = qs[p*16+r];
    float qsv= qs[p*16+s];
    akq += kr*qsv;
    akk += kr*ks_;
    aqq += qr*qsv;
  }
  float* Gb=G + b*768;
  atomicAdd(&Gb[t], akq);
  atomicAdd(&Gb[256+t], akk);
  atomicAdd(&Gb[512+t], aqq);
}

// A2: per (b,h): attn from Gram -> fold into M_b[16,64]. Wave-parallel softmax.
__global__ void k_attn(const float* G, float* Mb, const void* We,
                       const void* Wproj, const void* resc, const int* flg){
  int bf=*flg;
  __shared__ float wes[16*64];
  __shared__ float gkq[256], gkk[256], gqq[256];
  __shared__ float ukq[64*16], ukk[64*16], uqq[64*16];
  __shared__ float nk[64], nq[64];
  __shared__ float A[64*64];
  __shared__ float T[64*16];
  __shared__ float wpj[64*64];
  int b=blockIdx.x>>3, h=blockIdx.x&7;
  int t=threadIdx.x;
  for(int i=t;i<1024;i+=256){ int rr=i>>6, e=i&63; wes[rr*64+e]=LD(We, (long)rr*512 + h*64 + e, bf); }
  gkq[t]=G[b*768+t]; gkk[t]=G[b*768+256+t]; gqq[t]=G[b*768+512+t];
  for(int i=t;i<4096;i+=256){ int d=i>>6, c=i&63; wpj[i]=LD(Wproj,(long)(h*64+d)*64+c,bf); }
  __syncthreads();
  for(int i=t;i<1024;i+=256){
    int d=i>>4, s=i&15;
    float a1=0.f,a2=0.f,a3=0.f;
    for(int rr=0;rr<16;rr++){ float wv=wes[rr*64+d]; a1+=wv*gkq[rr*16+s]; a2+=wv*gkk[rr*16+s]; a3+=wv*gqq[rr*16+s]; }
    ukq[i]=a1; ukk[i]=a2; uqq[i]=a3;
  }
  __syncthreads();
  if(t<64){ float a=0.f; for(int s=0;s<16;s++) a+=ukk[t*16+s]*wes[s*64+t]; nk[t]=fmaxf(sqrtf(a),1e-12f); }
  else if(t<128){ int e=t-64; float a=0.f; for(int s=0;s<16;s++) a+=uqq[e*16+s]*wes[s*64+e]; nq[e]=fmaxf(sqrtf(a),1e-12f); }
  __syncthreads();
  float rsc=LD(resc,h,bf);
  for(int i=t;i<4096;i+=256){
    int d=i>>6, e=i&63;
    float a=0.f; for(int s=0;s<16;s++) a+=ukq[d*16+s]*wes[s*64+e];
    A[i]=a/(nk[d]*nq[e])*rsc;
  }
  __syncthreads();
  {
    // wave-parallel softmax: 4 lanes per row d, 16 e each
    int d=t>>2, g=t&3, e0=g<<4;
    float m=-1e30f;
    for(int e=e0;e<e0+16;e++) m=fmaxf(m,A[d*64+e]);
    m=fmaxf(m,__shfl_xor(m,1,4));
    m=fmaxf(m,__shfl_xor(m,2,4));
    float sum=0.f;
    for(int e=e0;e<e0+16;e++){ float ev=expf(A[d*64+e]-m); A[d*64+e]=ev; sum+=ev; }
    sum+=__shfl_xor(sum,1,4);
    sum+=__shfl_xor(sum,2,4);
    float inv=1.f/sum;
    for(int e=e0;e<e0+16;e++) A[d*64+e]*=inv;
  }
  __syncthreads();
  for(int i=t;i<1024;i+=256){
    int d=i>>4, s=i&15;
    float a=0.f; for(int e=0;e<64;e++) a+=A[d*64+e]*wes[s*64+e];
    T[i]=a;
  }
  __syncthreads();
  for(int i=t;i<1024;i+=256){
    int s=i>>6, c=i&63;
    float a=0.f; for(int d=0;d<64;d++) a+=T[d*16+s]*wpj[d*64+c];
    atomicAdd(&Mb[b*1024 + s*64 + c], a);
  }
}

// EPI v3: 16px tiles, 1024 blocks (4 blocks/CU) — mlp_out + residual haar + IWT + @M_b + bproj
__global__ void k_epi2(const float* g96, const float* vd, const float* Mb_,
                       const void* wout_, const void* rs_, const void* bproj,
                       void* out, const int* flg){
  int bf=*flg;
  __shared__ __align__(16) float sg[16*104];    // g stage (-> overlaid by she[16*64])
  __shared__ __align__(16) float swt[48*100];   // wt^T, [cc][ch] stride 100
  __shared__ __align__(16) float smb[1024];
  __shared__ float sbias[64];
  int t=threadIdx.x;
  int b = blockIdx.x>>8;
  int rem = blockIdx.x&255;
  int gi = rem>>2;
  int gj0 = (rem&3)<<4;       // 16 half-pixels: gj0..gj0+15

  // ---- stage ----
  long gb = ((long)b*4096 + gi*64 + gj0)*96;
  for(int e=t;e<1536;e+=256){ int px=e/96, ch=e-px*96; sg[px*104+ch]=g96[gb+e]; }
  for(int e=t;e<4608;e+=256){ int cc=e/96, ch=e-cc*96; swt[cc*100+ch]=LD(wout_, e, bf); }
  for(int i=t;i<1024;i+=256) smb[i]=Mb_[b*1024+i];
  if(t<64) sbias[t]=LD(bproj,t,bf);
  __syncthreads();

  // ---- mlp_out GEMM: 16px x 48cc, thread = 1px x 3cc ----
  int px=t>>4, ccg=t&15;
  int cc0=ccg*3;
  float a0=0.f,a1=0.f,a2=0.f;
  const float4* g4=(const float4*)sg;
  const float4* w4=(const float4*)swt;
  #pragma unroll 4
  for(int ch4=0; ch4<24; ch4++){
    float4 ga=g4[px*26+ch4];
    float4 w0=w4[cc0*25+ch4], w1=w4[(cc0+1)*25+ch4], w2=w4[(cc0+2)*25+ch4];
    a0 += ga.x*w0.x+ga.y*w0.y+ga.z*w0.z+ga.w*w0.w;
    a1 += ga.x*w1.x+ga.y*w1.y+ga.z*w1.z+ga.w*w1.w;
    a2 += ga.x*w2.x+ga.y*w2.y+ga.z*w2.z+ga.w*w2.w;
  }
  __syncthreads();   // all reads of sg done; safe to overlay with she

  // ---- he tile (16px x 64) into LDS (overlays sg) ----
  float* she = sg;   // 1024 floats
  float rs=LD(rs_,0,bf);
  float accv[3]={a0,a1,a2};
  int gj=gj0+px;
  long vb=((long)(b*128+2*gi)*128 + 2*gj)*16;
  #pragma unroll
  for(int j=0;j<3;j++){
    int cc=cc0+j;
    int m=cc+16, c=m>>2, f=m&3;
    float a=vd[vb+c], bv=vd[vb+16+c], cv=vd[vb+2048+c], dv=vd[vb+2064+c];
    float hv;
    if(f==0)      hv=(a+bv+cv+dv);
    else if(f==1) hv=(a-bv+cv-dv);
    else if(f==2) hv=(a+bv-cv-dv);
    else          hv=(a-bv-cv+dv);
    she[px*64 + 16 + cc] = hv*0.5f + rs*accv[j];
  }
  {
    int c16=ccg;          // 16px x 16 c16 = 256, one per thread
    int c=c16>>2, f=c16&3;
    float a=vd[vb+c], bv=vd[vb+16+c], cv=vd[vb+2048+c], dv=vd[vb+2064+c];
    float hv;
    if(f==0)      hv=(a+bv+cv+dv);
    else if(f==1) hv=(a-bv+cv-dv);
    else if(f==2) hv=(a+bv-cv-dv);
    else          hv=(a-bv-cv+dv);
    she[px*64 + c16] = hv*0.5f;
  }
  __syncthreads();

  // ---- output: 2 rows x 32 cols x 64 ch ----
  int c=t&63, xg=t>>6;
  float mbr[16];
  #pragma unroll
  for(int s=0;s<16;s++) mbr[s]=smb[s*64+c];
  float bb=sbias[c];
  long ob0 = ((long)(b*128+2*gi)*128 + 2*gj0)*64;
  for(int k=0;k<16;k++){
    int o=xg+(k<<2);        // [0,64)
    int r=o>>5, xl=o&31;
    int hp=xl>>1, pos=((r&1)<<1)|(xl&1);
    const float4* h4=(const float4*)(she + hp*64 + pos*16);
    float4 h0=h4[0],h1=h4[1],h2=h4[2],h3=h4[3];
    float acc=bb;
    acc += h0.x*mbr[0]+h0.y*mbr[1]+h0.z*mbr[2]+h0.w*mbr[3];
    acc += h1.x*mbr[4]+h1.y*mbr[5]+h1.z*mbr[6]+h1.w*mbr[7];
    acc += h2.x*mbr[8]+h2.y*mbr[9]+h2.z*mbr[10]+h2.w*mbr[11];
    acc += h3.x*mbr[12]+h3.y*mbr[13]+h3.z*mbr[14]+h3.w*mbr[15];
    long oo = ob0 + (long)r*8192 + (long)xl*64 + c;
    if(bf) ((__hip_bfloat16*)out)[oo]=__float2bfloat16(acc);
    else   ((float*)out)[oo]=acc;
  }
}

extern "C" void kernel_launch(void* const* d_in, const int* in_sizes, int n_in,
                              void* d_out, int out_size, void* d_ws, size_t ws_size,
                              hipStream_t stream) {
  const void* x_in   = d_in[0];
  const void* Wq     = d_in[1];
  const void* Wk     = d_in[2];
  const void* Wv     = d_in[3];
  const void* Wr     = d_in[4];
  const void* We     = d_in[5];
  const void* qs_dw  = d_in[6];
  const void* qs_pw  = d_in[7];
  const void* qs_g   = d_in[8];
  const void* al_pw  = d_in[9];
  const void* al_dw  = d_in[10];
  const void* ah_pw  = d_in[11];
  const void* ah_dw  = d_in[12];
  const void* ph_pw  = d_in[13];
  const void* ph_s   = d_in[14];
  const void* bn_g   = d_in[15];
  const void* bn_b   = d_in[16];
  const void* mlp_in = d_in[17];
  const void* mlp_dw = d_in[18];
  const void* mlp_out= d_in[19];
  const void* res_s  = d_in[20];
  const void* rescale= d_in[21];
  const void* Wproj  = d_in[22];
  const void* bproj  = d_in[23];
  float* ws = (float*)d_ws;
  const int* flg = ((const int*)ws) + OFF_FLAG;

  float* FA = ws + OFF_S;
  float* FB = FA + FSZ;
  float* FC = FB + FSZ;
  float* FD = FC + FSZ;
  float* FE = FD + FSZ;
  float* M96 = FE + FSZ;            // 1.5M floats
  float* G96 = ws + OFF_QDIM;       // overlays dead qd/kd (dead after k_mix3)

  k_head<<<49,256,0,stream>>>(Wq,Wk,Wv,Wr,bn_g, ws);
  k_dims<<<512,256,0,stream>>>(x_in, ws, ws+OFF_QDIM, ws+OFF_KDIM, ws+OFF_VDIM, flg);
  // spatial(q) || fft_row(k) || wave_a(v)
  k_mix3<<<1024,256,0,stream>>>(ws+OFF_QDIM, ws+OFF_QMIX, qs_dw, qs_pw, qs_g,
                                ws+OFF_KDIM, FA, FB,
                                ws+OFF_VDIM, M96, mlp_in, bn_g, bn_b, flg);
  // col fft(k) || wave_dw chunk 0
  k_fft_col<<<2308,256,0,stream>>>(FA, FB, FC, FD, FE, al_pw, ah_pw, ph_pw, ph_s,
                                   M96, G96, mlp_dw, flg);
  // dw+Y+inverse col fft(k) || wave_dw chunk 1
  k_ifft_four<<<2308,256,0,stream>>>(FC, FD, FE, FA, FB, al_dw, ah_dw,
                                     M96, G96, mlp_dw, flg);
  // ifft_row(k)+gram || wave_dw chunk 2
  k_irow_gram<<<2304,256,0,stream>>>(FA, FB, ws+OFF_QMIX, ws+OFF_G, M96, G96, mlp_dw, flg);
  k_attn<<<32,256,0,stream>>>(ws+OFF_G, ws+OFF_MB, We, Wproj, rescale, flg);
  k_epi2<<<1024,256,0,stream>>>(G96, ws+OFF_VDIM, ws+OFF_MB, mlp_out, res_s, bproj, d_out, flg);
}

// Round 8
// 262.950 us; speedup vs baseline: 1.0339x; 1.0339x over previous
//
#include <hip/hip_runtime.h>
#include <hip/hip_bf16.h>
#include <math.h>

#define HW 16384

__device__ __forceinline__ float LD(const void* p, long i, int bf){
  return bf ? __bfloat162float(((const __hip_bfloat16*)p)[i]) : ((const float*)p)[i];
}
__device__ __forceinline__ float geluf(float x){ return 0.5f*x*(1.0f + erff(x*0.70710678118654752f)); }
__device__ __forceinline__ int rev7(int i){ return (int)(__brev((unsigned)i)>>25); }

__device__ __forceinline__ void fft128(float* Ar, float* Ai, const float* ct, const float* st,
                                       int lane, float dir){
  #pragma unroll
  for(int len=2; len<=128; len<<=1){
    int half=len>>1;
    int pos = lane & (half-1);
    int i1 = ((lane & ~(half-1))<<1) | pos;
    int i2 = i1 + half;
    int tw = pos * (128/len);
    float wr = ct[tw], wi = dir*st[tw];
    float xr=Ar[i2], xi=Ai[i2];
    float tr = xr*wr - xi*wi;
    float ti = xr*wi + xi*wr;
    float ur=Ar[i1], ui=Ai[i1];
    Ar[i1]=ur+tr; Ai[i1]=ui+ti;
    Ar[i2]=ur-tr; Ai[i2]=ui-ti;
  }
}

#define MAKE_TWP(ct,st) { int tt=threadIdx.x; if(tt<128){ float ang=6.283185307179586f*(float)tt/128.f; float s_,c_; sincosf(ang,&s_,&c_); (ct)[tt]=c_; (st)[tt]=s_; } }

// ---- ws layout (float offsets) ----
#define OFF_M    0
#define OFF_G    3072
#define OFF_MB   6144
#define OFF_FLAG 10240
#define OFF_QDIM 16384
#define OFF_KDIM (16384 + 1048576)
#define OFF_VDIM (16384 + 2*1048576)
#define OFF_QMIX (16384 + 3*1048576)
#define OFF_KMIX (16384 + 4*1048576)
#define OFF_S    (16384 + 5*1048576)
#define FSZ 532480            // 4*128*65*16
// FA..FE = OFF_S..+5*FSZ ; M96 = FE+FSZ (1.5M) ; G96 overlays dead qd/kd @OFF_QDIM

// ---- shared wave_dw body: m96 -> g96, o in [0, 1572864) ----
__device__ __forceinline__ void wave_dw_body(int o, const float* m96, float* g96, const float* wdw){
  int ch = o%96; int r = o/96; int px = r&4095; int b = r>>12;
  int i = px>>6, j = px&63;
  long mb = (long)b*393216;
  float acc=0.f;
  for(int dp=0;dp<3;dp++){ int ii=i-1+dp; if(ii<0||ii>=64) continue;
    for(int dq=0;dq<3;dq++){ int jj=j-1+dq; if(jj<0||jj>=64) continue;
      acc += wdw[ch*9+dp*3+dq]*m96[mb + (long)(ii*64+jj)*96 + ch]; } }
  g96[o]=geluf(acc);
}

// K0: fold (48 blocks) + flag/zero (block 48)
// M stored as ws[cc*48 + mat*16 + rr]   ([c][48] layout for k_dims v3)
__global__ void k_head(const void* Wq, const void* Wk, const void* Wv,
                       const void* Wr, const void* bng, float* ws){
  __shared__ float wr[8192];
  __shared__ float part[256];
  int blk=blockIdx.x, t=threadIdx.x;
  if(blk==48){
    for(int i=3072+t;i<10240;i+=256) ws[i]=0.f;
    if(t==0){
      float v = ((const float*)bng)[0];
      ((int*)ws)[OFF_FLAG] = (v==1.0f) ? 0 : 1;
    }
    return;
  }
  int bf = (((const float*)bng)[0]==1.0f) ? 0 : 1;
  int mat=blk>>4, seg=blk&15;
  const void* Wsrc = mat==0 ? Wq : (mat==1 ? Wk : Wv);
  for(int i=t;i<8192;i+=256) wr[i]=LD(Wr,i,bf);
  __syncthreads();
  int o=t&63, jseg=t>>6;
  int c=seg*4+(o>>4), r=o&15;
  float acc=0.f;
  for(int j=jseg*128;j<jseg*128+128;j++) acc += LD(Wsrc,(long)c*512+j,bf)*wr[j*16+r];
  part[jseg*64+o]=acc;
  __syncthreads();
  if(t<64){
    float s=part[t]+part[64+t]+part[128+t]+part[192+t];
    int cc=seg*4+(t>>4), rr=t&15;
    ws[cc*48 + mat*16 + rr]=s;   // [c][48] layout
  }
}

// K1 v3: q/k/v_dim = x @ M. LDS register-tiled GEMM.
__global__ void k_dims(const void* x, const float* ws,
                       float* qd, float* kd, float* vd, const int* flg){
  int bf=*flg;
  __shared__ __align__(16) float ms[3072];       // [c][48]
  __shared__ __align__(16) float xs[64*130];     // [c][px], stride 130
  int t=threadIdx.x;
  int b = blockIdx.x>>7;
  int pix0 = (blockIdx.x&127)<<7;
  for(int i=t;i<3072;i+=256) ms[i]=ws[i];
  long base = ((long)b*HW + pix0)*64;
  if(!bf){
    const float4* xp = (const float4*)((const float*)x + base);
    for(int e=t;e<2048;e+=256){
      int px=e>>4, c4=(e&15)<<2;
      float4 v = xp[e];
      xs[(c4  )*130+px]=v.x; xs[(c4+1)*130+px]=v.y;
      xs[(c4+2)*130+px]=v.z; xs[(c4+3)*130+px]=v.w;
    }
  } else {
    const uint4* xp = (const uint4*)((const __hip_bfloat16*)x + base);
    for(int e=t;e<1024;e+=256){
      int px=e>>3, c8=(e&7)<<3;
      uint4 u = xp[e];
      unsigned uu[4]={u.x,u.y,u.z,u.w};
      #pragma unroll
      for(int q=0;q<4;q++){
        xs[(c8+2*q  )*130+px] = __uint_as_float((uu[q]&0xffffu)<<16);
        xs[(c8+2*q+1)*130+px] = __uint_as_float(uu[q]&0xffff0000u);
      }
    }
  }
  __syncthreads();
  int pxg=t>>2, rg=t&3;
  int px0=pxg<<1, r0=rg*12;
  float acc0[12], acc1[12];
  #pragma unroll
  for(int j=0;j<12;j++){ acc0[j]=0.f; acc1[j]=0.f; }
  #pragma unroll 4
  for(int c=0;c<64;c++){
    float2 xv = *(const float2*)&xs[c*130+px0];
    const float4* mp = (const float4*)&ms[c*48+r0];
    float4 m0=mp[0], m1=mp[1], m2=mp[2];
    acc0[0]+=xv.x*m0.x; acc0[1]+=xv.x*m0.y; acc0[2]+=xv.x*m0.z; acc0[3]+=xv.x*m0.w;
    acc0[4]+=xv.x*m1.x; acc0[5]+=xv.x*m1.y; acc0[6]+=xv.x*m1.z; acc0[7]+=xv.x*m1.w;
    acc0[8]+=xv.x*m2.x; acc0[9]+=xv.x*m2.y; acc0[10]+=xv.x*m2.z; acc0[11]+=xv.x*m2.w;
    acc1[0]+=xv.y*m0.x; acc1[1]+=xv.y*m0.y; acc1[2]+=xv.y*m0.z; acc1[3]+=xv.y*m0.w;
    acc1[4]+=xv.y*m1.x; acc1[5]+=xv.y*m1.y; acc1[6]+=xv.y*m1.z; acc1[7]+=xv.y*m1.w;
    acc1[8]+=xv.y*m2.x; acc1[9]+=xv.y*m2.y; acc1[10]+=xv.y*m2.z; acc1[11]+=xv.y*m2.w;
  }
  __syncthreads();     // xs reads done -> overlay with sh[128][49]
  float* sh = xs;
  #pragma unroll
  for(int j=0;j<12;j++){
    sh[(px0  )*49 + r0+j] = acc0[j];
    sh[(px0+1)*49 + r0+j] = acc1[j];
  }
  __syncthreads();
  long ob = ((long)b*HW + pix0)*16;
  for(int e=t;e<2048;e+=256){
    int px=e>>4, rr=e&15;
    qd[ob+e]=sh[px*49 + rr];
    kd[ob+e]=sh[px*49 + 16 + rr];
    vd[ob+e]=sh[px*49 + 32 + rr];
  }
}

// K2 merged: [0,256) spatial (2 rows/blk, f2-vectorized) | [256,512) fft_row | [512,1024) wave_a v3
__global__ void k_mix3(const float* qd, float* qm, const void* dw, const void* pw, const void* gamma,
                       const float* kd, float* Rre, float* Rim,
                       const float* vd, float* m96, const void* win, const void* bng, const void* bnb,
                       const int* flg){
  __shared__ __align__(16) float smem[9664];
  int bf=*flg;
  int blk=blockIdx.x, t=threadIdx.x;
  if(blk<256){
    // ---- SpitialUnit, 2 y-rows per block, float2 channel-vectorized ----
    float* tile=smem;                 // [4*128][18] = 9216
    float* dws=smem+9216;             // [tap][16] = 144
    float* pws=smem+9360;             // [c][16]  = 256
    float* gsm=smem+9616;             // 16
    int b=blk>>6, y0=(blk&63)<<1;
    for(int i=t;i<144;i+=256){ int tap=i>>4, ch=i&15; dws[i]=LD(dw,ch*9+tap,bf); }
    if(t<256) pws[t]=LD(pw,t,bf);
    if(t<16) gsm[t]=LD(gamma,t,bf);
    for(int i=t;i<8192;i+=256){
      int ry=i>>11, rem=i&2047, xx=rem>>4, ch=rem&15;
      int yy=y0-1+ry;
      tile[(ry*128+xx)*18+ch] = (yy>=0&&yy<128) ? qd[(long)(b*128+yy)*2048 + rem] : 0.f;
    }
    __syncthreads();
    int ty=t>>7, x=t&127;
    float2 g2[8];
    #pragma unroll
    for(int k=0;k<8;k++){ g2[k].x=0.f; g2[k].y=0.f; }
    for(int p=0;p<3;p++){
      int row=ty+p;
      for(int q=0;q<3;q++){
        int xx=x-1+q;
        if(xx<0||xx>=128) continue;
        const float2* tv=(const float2*)&tile[(row*128+xx)*18];
        const float2* wv=(const float2*)&dws[(p*3+q)*16];
        #pragma unroll
        for(int k=0;k<8;k++){
          float2 tt=tv[k], ww=wv[k];
          g2[k].x += ww.x*tt.x; g2[k].y += ww.y*tt.y;
        }
      }
    }
    float ge[16];
    #pragma unroll
    for(int k=0;k<8;k++){ ge[2*k]=geluf(g2[k].x); ge[2*k+1]=geluf(g2[k].y); }
    long ob = ((long)(b*128+y0+ty)*128 + x)*16;
    for(int c=0;c<16;c++){
      const float2* pv=(const float2*)&pws[c*16];
      float acc=0.f;
      #pragma unroll
      for(int k=0;k<8;k++){ float2 pp=pv[k]; acc += pp.x*ge[2*k]+pp.y*ge[2*k+1]; }
      qm[ob+c] = tile[((1+ty)*128+x)*18+c] + gsm[c]*acc;
    }
  } else if(blk<512){
    // ---- row rfft: kd NHWC -> R[b][y][v][c] ----
    float* slab=smem; float* outre=smem+4160; float* outim=smem+6272;
    float* Ar=smem+8384; float* Ai=smem+8896; float* ct=smem+9408; float* st=smem+9536;
    int blk2=blk-256;
    int b=blk2>>6, y0=(blk2&63)<<1;
    MAKE_TWP(ct,st);
    long gbase = ((long)(b*128+y0))*2048;
    for(int e=t;e<4096;e+=256){
      int yl=e>>11, rem=e&2047, x=rem>>4, c=rem&15;
      slab[yl*2080 + c*130 + x] = kd[gbase + e];
    }
    __syncthreads();
    int w=t>>6, l=t&63, wb=w<<7;
    for(int li=w; li<32; li+=4){
      int yl=li>>4, c=li&15;
      int sb = yl*2080 + c*130;
      float v0=slab[sb+l], v1=slab[sb+64+l];
      int r0=rev7(l), r1=rev7(64+l);
      Ar[wb+r0]=v0; Ai[wb+r0]=0.f;
      Ar[wb+r1]=v1; Ai[wb+r1]=0.f;
      fft128(Ar+wb, Ai+wb, ct, st, l, -1.f);
      int ob = yl*1056 + c*66;
      outre[ob+l]=Ar[wb+l]; outim[ob+l]=Ai[wb+l];
      if(l==0){ outre[ob+64]=Ar[wb+64]; outim[ob+64]=Ai[wb+64]; }
    }
    __syncthreads();
    long obase = ((long)(b*128+y0))*1040;
    for(int e=t;e<2080;e+=256){
      int yl=e/1040, rem=e%1040, v=rem>>4, c=rem&15;
      Rre[obase+e]=outre[yl*1056 + c*66 + v];
      Rim[obase+e]=outim[yl*1056 + c*66 + v];
    }
  } else {
    // ---- wave_a v3: haar + BN + mlp_in (48->96) -> m96, register-tiled GEMM ----
    float* wiT=smem;                  // [cc][96] stride 100 = 4800
    float* vds=smem+4800;             // 2048 (2 rows x 64 px x 16)
    float* ns =smem+6848;             // [32 hp][48] stride 49 = 1568
    float* gsm=smem+8416;             // 48
    float* bsm=smem+8464;             // 48
    int blk3=blk-512;                 // [0,512)
    int b = blk3>>7;
    int hpbase = (blk3&127)<<5;       // 32 hp per block (half row of j)
    int i0 = hpbase>>6, j0 = hpbase&63;
    for(int i=t;i<4608;i+=256){ int ch=i/48, cc=i-ch*48; wiT[cc*100+ch]=LD(win,i,bf); }
    if(t<48){ gsm[t]=LD(bng,t,bf)*(1.f/sqrtf(1.f+1e-5f)); bsm[t]=LD(bnb,t,bf); }
    long rb0 = ((long)(b*128 + 2*i0)*128 + 2*j0)*16;
    {
      const float4* v4a=(const float4*)(vd+rb0);
      const float4* v4b=(const float4*)(vd+rb0+2048);
      ((float4*)vds)[t] = v4a[t];
      ((float4*)(vds+1024))[t] = v4b[t];
    }
    __syncthreads();
    for(int o=t;o<1536;o+=256){
      int p=o/48, cc=o-p*48;
      int m=cc+16, c=m>>2, f=m&3;
      float a =vds[(2*p)*16+c],      bv=vds[(2*p+1)*16+c];
      float cv=vds[1024+(2*p)*16+c], dvv=vds[1024+(2*p+1)*16+c];
      float v;
      if(f==0)      v=(a+bv+cv+dvv);
      else if(f==1) v=(a-bv+cv-dvv);
      else if(f==2) v=(a+bv-cv-dvv);
      else          v=(a-bv-cv+dvv);
      ns[p*49+cc] = v*0.5f*gsm[cc]+bsm[cc];
    }
    __syncthreads();
    int px=t>>3, chg=t&7;
    int ch0=chg*12;
    float4 a0={0,0,0,0}, a1={0,0,0,0}, a2={0,0,0,0};
    #pragma unroll 4
    for(int cc=0;cc<48;cc++){
      float nsv = ns[px*49+cc];
      const float4* wp = (const float4*)&wiT[cc*100+ch0];
      float4 w0=wp[0], w1=wp[1], w2=wp[2];
      a0.x+=nsv*w0.x; a0.y+=nsv*w0.y; a0.z+=nsv*w0.z; a0.w+=nsv*w0.w;
      a1.x+=nsv*w1.x; a1.y+=nsv*w1.y; a1.z+=nsv*w1.z; a1.w+=nsv*w1.w;
      a2.x+=nsv*w2.x; a2.y+=nsv*w2.y; a2.z+=nsv*w2.z; a2.w+=nsv*w2.w;
    }
    long ob = ((long)b*4096 + hpbase + px)*96 + ch0;
    float4* mp=(float4*)(m96+ob);
    mp[0]=a0; mp[1]=a1; mp[2]=a2;
  }
}

// F2+F3: [0,260) col fft over y, amp/phase, masked mix + gelu | [260,2308) wave_dw chunk 0
__global__ void k_fft_col(const float* Rre, const float* Rim,
                          float* glo, float* ghi, float* pho,
                          const void* alpw, const void* ahpw,
                          const void* phpw, const void* phs,
                          const float* m96, float* g96, const void* wdw_,
                          const int* flg){
  __shared__ float sre[2080], sim[2080];
  __shared__ float og[2080], oh[2080], op[2080];
  __shared__ float Ar[512], Ai[512];
  __shared__ float ct[128], st[128];
  __shared__ float wl[256], wh[256], wp[256];
  int t=threadIdx.x;
  int bf=*flg;
  int blk=blockIdx.x;
  if(blk>=260){
    float* wdw=sre;  // 864 fits
    for(int i=t;i<864;i+=256) wdw[i]=LD(wdw_,i,bf);
    __syncthreads();
    wave_dw_body((blk-260)*256+t, m96, g96, wdw);
    return;
  }
  int b = blk/65, v = blk%65;
  MAKE_TWP(ct,st);
  wl[t]=LD(alpw,t,bf); wh[t]=LD(ahpw,t,bf); wp[t]=LD(phpw,t,bf);
  long ibase = ((long)b*128)*1040 + v*16;
  for(int e=t;e<2048;e+=256){
    int y=e>>4, c=e&15;
    sre[c*130+y]=Rre[ibase + (long)y*1040 + c];
    sim[c*130+y]=Rim[ibase + (long)y*1040 + c];
  }
  __syncthreads();
  int w=t>>6, l=t&63, wb=w<<7;
  const float inv=1.f/128.f;
  for(int c=w; c<16; c+=4){
    int sb=c*130;
    float x0r=sre[sb+l], x0i=sim[sb+l], x1r=sre[sb+64+l], x1i=sim[sb+64+l];
    int r0=rev7(l), r1=rev7(64+l);
    Ar[wb+r0]=x0r; Ai[wb+r0]=x0i;
    Ar[wb+r1]=x1r; Ai[wb+r1]=x1i;
    fft128(Ar+wb, Ai+wb, ct, st, l, -1.f);
    float re0=Ar[wb+l]*inv, im0=Ai[wb+l]*inv;
    float re1=Ar[wb+64+l]*inv, im1=Ai[wb+64+l]*inv;
    sre[sb+l]=sqrtf(re0*re0+im0*im0); sim[sb+l]=atan2f(im0,re0);
    sre[sb+64+l]=sqrtf(re1*re1+im1*im1); sim[sb+64+l]=atan2f(im1,re1);
  }
  __syncthreads();
  {
    int u = t&127, half = t>>7;
    float yy=(float)u/127.f, xx=(float)v/64.f;
    float rr=sqrtf(yy*yy+xx*xx);
    float lo = 1.f/(1.f+expf((rr-0.25f)*20.f));
    float hi = 1.f-lo;
    float av[16], pv[16];
    for(int ch=0;ch<16;ch++){ av[ch]=sre[ch*130+u]; pv[ch]=sim[ch*130+u]; }
    float pscale = LD(phs,0,bf);
    for(int c=half*8;c<half*8+8;c++){
      float al=0.f, ah=0.f, pp=0.f;
      for(int ch=0;ch<16;ch++){
        float a=av[ch];
        al += wl[c*16+ch]*(a*lo);
        ah += wh[c*16+ch]*(a*hi);
        pp += wp[c*16+ch]*pv[ch];
      }
      og[c*130+u]=geluf(al); oh[c*130+u]=geluf(ah); op[c*130+u]=pv[c]+pscale*pp;
    }
  }
  __syncthreads();
  long obase = ((long)b*128)*1040 + v*16;
  for(int e=t;e<2048;e+=256){
    int u=e>>4, c=e&15;
    long o = obase + (long)u*1040 + c;
    glo[o]=og[c*130+u]; ghi[o]=oh[c*130+u]; pho[o]=op[c*130+u];
  }
}

// F4: depthwise 3x3 over (u,v) + Y = amp*e^{i phase}
__global__ void k_four_dw(const float* glo, const float* ghi, const float* pho,
                          float* Yre, float* Yim,
                          const void* aldw, const void* ahdw, const int* flg){
  int bf=*flg;
  __shared__ float wl[144], wh[144];
  int t=threadIdx.x;
  if(t<144){wl[t]=LD(aldw,t,bf); wh[t]=LD(ahdw,t,bf);}
  __syncthreads();
  long o = (long)blockIdx.x*256+t;  // 532480 exact
  int c=(int)(o&15); long r=o>>4; int v=(int)(r%65); long r2=r/65; int u=(int)(r2&127); int b=(int)(r2>>7);
  float acc=0.f;
  for(int dp=0;dp<3;dp++){
    int uu=u-1+dp; if(uu<0||uu>=128) continue;
    for(int dq=0;dq<3;dq++){
      int vv=v-1+dq; if(vv<0||vv>=65) continue;
      long idx=(((long)(b*128+uu))*65+vv)*16+c;
      acc += wl[c*9+dp*3+dq]*glo[idx] + wh[c*9+dp*3+dq]*ghi[idx];
    }
  }
  float pvv = pho[o];
  float s_,c_; sincosf(pvv,&s_,&c_);
  Yre[o]=acc*c_; Yim[o]=acc*s_;
}

// I1: [0,260) inverse col fft over u | [260,2308) wave_dw chunk 1
__global__ void k_ifft_col(const float* Yre, const float* Yim, float* Zre, float* Zim,
                           const float* m96, float* g96, const void* wdw_, const int* flg){
  __shared__ float sre[2080], sim[2080];
  __shared__ float Ar[512], Ai[512];
  __shared__ float ct[128], st[128];
  int t=threadIdx.x;
  int blk=blockIdx.x;
  if(blk>=260){
    int bf=*flg;
    float* wdw=sre;  // 864 fits
    for(int i=t;i<864;i+=256) wdw[i]=LD(wdw_,i,bf);
    __syncthreads();
    wave_dw_body((blk-260+2048)*256+t, m96, g96, wdw);
    return;
  }
  int b = blk/65, v = blk%65;
  MAKE_TWP(ct,st);
  long ibase = ((long)b*128)*1040 + v*16;
  for(int e=t;e<2048;e+=256){
    int u=e>>4, c=e&15;
    sre[c*130+u]=Yre[ibase + (long)u*1040 + c];
    sim[c*130+u]=Yim[ibase + (long)u*1040 + c];
  }
  __syncthreads();
  int w=t>>6, l=t&63, wb=w<<7;
  for(int c=w; c<16; c+=4){
    int sb=c*130;
    float x0r=sre[sb+l], x0i=sim[sb+l], x1r=sre[sb+64+l], x1i=sim[sb+64+l];
    int r0=rev7(l), r1=rev7(64+l);
    Ar[wb+r0]=x0r; Ai[wb+r0]=x0i;
    Ar[wb+r1]=x1r; Ai[wb+r1]=x1i;
    fft128(Ar+wb, Ai+wb, ct, st, l, +1.f);
    sre[sb+l]=Ar[wb+l]; sim[sb+l]=Ai[wb+l];
    sre[sb+64+l]=Ar[wb+64+l]; sim[sb+64+l]=Ai[wb+64+l];
  }
  __syncthreads();
  for(int e=t;e<2048;e+=256){
    int y=e>>4, c=e&15;
    Zre[ibase + (long)y*1040 + c]=sre[c*130+y];
    Zim[ibase + (long)y*1040 + c]=sim[c*130+y];
  }
}

// K3: [0,256) ifft_row + fused gram -> atomicAdd G | [256,2304) wave_dw chunk 2
__global__ void k_irow_gram(const float* Zre, const float* Zim, const float* qm,
                            float* G, const float* m96, float* g96, const void* wdw_,
                            const int* flg){
  __shared__ float smem[9664];
  int blk=blockIdx.x, t=threadIdx.x;
  if(blk>=256){
    int bf=*flg;
    float* wdw=smem;
    for(int i=t;i<864;i+=256) wdw[i]=LD(wdw_,i,bf);
    __syncthreads();
    wave_dw_body((blk-256+4096)*256+t, m96, g96, wdw);
    return;
  }
  float* szre=smem; float* szim=smem+2112; float* oslab=smem+4224;
  float* Ar=smem+8384; float* Ai=smem+8896; float* ct=smem+9408; float* st=smem+9536;
  int b = blk>>6, y0 = (blk&63)<<1;
  MAKE_TWP(ct,st);
  long ibase = ((long)(b*128+y0))*1040;
  for(int e=t;e<2080;e+=256){
    int yl=e/1040, rem=e%1040, v=rem>>4, c=rem&15;
    szre[yl*1056 + c*66 + v]=Zre[ibase+e];
    szim[yl*1056 + c*66 + v]=Zim[ibase+e];
  }
  __syncthreads();
  int w=t>>6, l=t&63, wb=w<<7;
  const float inv=1.f/128.f;
  for(int li=w; li<32; li+=4){
    int yl=li>>4, c=li&15;
    int sb = yl*1056 + c*66;
    float zr0 = szre[sb+l];
    float zi0 = (l==0)?0.f:szim[sb+l];
    float zr1, zi1;
    if(l==0){ zr1=szre[sb+64]; zi1=0.f; }
    else    { zr1=szre[sb+64-l]; zi1=-szim[sb+64-l]; }
    int r0=rev7(l), r1=rev7(64+l);
    Ar[wb+r0]=zr0; Ai[wb+r0]=zi0;
    Ar[wb+r1]=zr1; Ai[wb+r1]=zi1;
    fft128(Ar+wb, Ai+wb, ct, st, l, +1.f);
    int ob = yl*2080 + c*130;
    oslab[ob+l]=Ar[wb+l]*inv;
    oslab[ob+64+l]=Ar[wb+64+l]*inv;
  }
  __syncthreads();
  // ---- fused gram: km tile is in oslab; stage qm rows into szre region ----
  float* qs = smem;   // 4096 floats (overlays szre+szim, dead now)
  long qbase = ((long)(b*128+y0))*2048;
  for(int e=t;e<4096;e+=256) qs[e]=qm[qbase+e];
  __syncthreads();
  int r=t>>4, s=t&15;
  float akq=0.f, akk=0.f, aqq=0.f;
  for(int p=0;p<256;p++){
    int yl=p>>7, x=p&127;
    float kr = oslab[yl*2080 + r*130 + x];
    float ks_ = oslab[yl*2080 + s*130 + x];
    float qr = qs[p*16+r];
    float qsv= qs[p*16+s];
    akq += kr*qsv;
    akk += kr*ks_;
    aqq += qr*qsv;
  }
  float* Gb=G + b*768;
  atomicAdd(&Gb[t], akq);
  atomicAdd(&Gb[256+t], akk);
  atomicAdd(&Gb[512+t], aqq);
}

// A2: per (b,h): attn from Gram -> fold into M_b[16,64]. Wave-parallel softmax.
__global__ void k_attn(const float* G, float* Mb, const void* We,
                       const void* Wproj, const void* resc, const int* flg){
  int bf=*flg;
  __shared__ float wes[16*64];
  __shared__ float gkq[256], gkk[256], gqq[256];
  __shared__ float ukq[64*16], ukk[64*16], uqq[64*16];
  __shared__ float nk[64], nq[64];
  __shared__ float A[64*64];
  __shared__ float T[64*16];
  __shared__ float wpj[64*64];
  int b=blockIdx.x>>3, h=blockIdx.x&7;
  int t=threadIdx.x;
  for(int i=t;i<1024;i+=256){ int rr=i>>6, e=i&63; wes[rr*64+e]=LD(We, (long)rr*512 + h*64 + e, bf); }
  gkq[t]=G[b*768+t]; gkk[t]=G[b*768+256+t]; gqq[t]=G[b*768+512+t];
  for(int i=t;i<4096;i+=256){ int d=i>>6, c=i&63; wpj[i]=LD(Wproj,(long)(h*64+d)*64+c,bf); }
  __syncthreads();
  for(int i=t;i<1024;i+=256){
    int d=i>>4, s=i&15;
    float a1=0.f,a2=0.f,a3=0.f;
    for(int rr=0;rr<16;rr++){ float wv=wes[rr*64+d]; a1+=wv*gkq[rr*16+s]; a2+=wv*gkk[rr*16+s]; a3+=wv*gqq[rr*16+s]; }
    ukq[i]=a1; ukk[i]=a2; uqq[i]=a3;
  }
  __syncthreads();
  if(t<64){ float a=0.f; for(int s=0;s<16;s++) a+=ukk[t*16+s]*wes[s*64+t]; nk[t]=fmaxf(sqrtf(a),1e-12f); }
  else if(t<128){ int e=t-64; float a=0.f; for(int s=0;s<16;s++) a+=uqq[e*16+s]*wes[s*64+e]; nq[e]=fmaxf(sqrtf(a),1e-12f); }
  __syncthreads();
  float rsc=LD(resc,h,bf);
  for(int i=t;i<4096;i+=256){
    int d=i>>6, e=i&63;
    float a=0.f; for(int s=0;s<16;s++) a+=ukq[d*16+s]*wes[s*64+e];
    A[i]=a/(nk[d]*nq[e])*rsc;
  }
  __syncthreads();
  {
    // wave-parallel softmax: 4 lanes per row d, 16 e each
    int d=t>>2, g=t&3, e0=g<<4;
    float m=-1e30f;
    for(int e=e0;e<e0+16;e++) m=fmaxf(m,A[d*64+e]);
    m=fmaxf(m,__shfl_xor(m,1,4));
    m=fmaxf(m,__shfl_xor(m,2,4));
    float sum=0.f;
    for(int e=e0;e<e0+16;e++){ float ev=expf(A[d*64+e]-m); A[d*64+e]=ev; sum+=ev; }
    sum+=__shfl_xor(sum,1,4);
    sum+=__shfl_xor(sum,2,4);
    float inv=1.f/sum;
    for(int e=e0;e<e0+16;e++) A[d*64+e]*=inv;
  }
  __syncthreads();
  for(int i=t;i<1024;i+=256){
    int d=i>>4, s=i&15;
    float a=0.f; for(int e=0;e<64;e++) a+=A[d*64+e]*wes[s*64+e];
    T[i]=a;
  }
  __syncthreads();
  for(int i=t;i<1024;i+=256){
    int s=i>>6, c=i&63;
    float a=0.f; for(int d=0;d<64;d++) a+=T[d*16+s]*wpj[d*64+c];
    atomicAdd(&Mb[b*1024 + s*64 + c], a);
  }
}

// EPI v3: 16px tiles, 1024 blocks (4 blocks/CU) — mlp_out + residual haar + IWT + @M_b + bproj
__global__ void k_epi2(const float* g96, const float* vd, const float* Mb_,
                       const void* wout_, const void* rs_, const void* bproj,
                       void* out, const int* flg){
  int bf=*flg;
  __shared__ __align__(16) float sg[16*104];    // g stage (-> overlaid by she[16*64])
  __shared__ __align__(16) float swt[48*100];   // wt^T, [cc][ch] stride 100
  __shared__ __align__(16) float smb[1024];
  __shared__ float sbias[64];
  int t=threadIdx.x;
  int b = blockIdx.x>>8;
  int rem = blockIdx.x&255;
  int gi = rem>>2;
  int gj0 = (rem&3)<<4;       // 16 half-pixels: gj0..gj0+15

  // ---- stage ----
  long gb = ((long)b*4096 + gi*64 + gj0)*96;
  for(int e=t;e<1536;e+=256){ int px=e/96, ch=e-px*96; sg[px*104+ch]=g96[gb+e]; }
  for(int e=t;e<4608;e+=256){ int cc=e/96, ch=e-cc*96; swt[cc*100+ch]=LD(wout_, e, bf); }
  for(int i=t;i<1024;i+=256) smb[i]=Mb_[b*1024+i];
  if(t<64) sbias[t]=LD(bproj,t,bf);
  __syncthreads();

  // ---- mlp_out GEMM: 16px x 48cc, thread = 1px x 3cc ----
  int px=t>>4, ccg=t&15;
  int cc0=ccg*3;
  float a0=0.f,a1=0.f,a2=0.f;
  const float4* g4=(const float4*)sg;
  const float4* w4=(const float4*)swt;
  #pragma unroll 4
  for(int ch4=0; ch4<24; ch4++){
    float4 ga=g4[px*26+ch4];
    float4 w0=w4[cc0*25+ch4], w1=w4[(cc0+1)*25+ch4], w2=w4[(cc0+2)*25+ch4];
    a0 += ga.x*w0.x+ga.y*w0.y+ga.z*w0.z+ga.w*w0.w;
    a1 += ga.x*w1.x+ga.y*w1.y+ga.z*w1.z+ga.w*w1.w;
    a2 += ga.x*w2.x+ga.y*w2.y+ga.z*w2.z+ga.w*w2.w;
  }
  __syncthreads();   // all reads of sg done; safe to overlay with she

  // ---- he tile (16px x 64) into LDS (overlays sg) ----
  float* she = sg;   // 1024 floats
  float rs=LD(rs_,0,bf);
  float accv[3]={a0,a1,a2};
  int gj=gj0+px;
  long vb=((long)(b*128+2*gi)*128 + 2*gj)*16;
  #pragma unroll
  for(int j=0;j<3;j++){
    int cc=cc0+j;
    int m=cc+16, c=m>>2, f=m&3;
    float a=vd[vb+c], bv=vd[vb+16+c], cv=vd[vb+2048+c], dv=vd[vb+2064+c];
    float hv;
    if(f==0)      hv=(a+bv+cv+dv);
    else if(f==1) hv=(a-bv+cv-dv);
    else if(f==2) hv=(a+bv-cv-dv);
    else          hv=(a-bv-cv+dv);
    she[px*64 + 16 + cc] = hv*0.5f + rs*accv[j];
  }
  {
    int c16=ccg;          // 16px x 16 c16 = 256, one per thread
    int c=c16>>2, f=c16&3;
    float a=vd[vb+c], bv=vd[vb+16+c], cv=vd[vb+2048+c], dv=vd[vb+2064+c];
    float hv;
    if(f==0)      hv=(a+bv+cv+dv);
    else if(f==1) hv=(a-bv+cv-dv);
    else if(f==2) hv=(a+bv-cv-dv);
    else          hv=(a-bv-cv+dv);
    she[px*64 + c16] = hv*0.5f;
  }
  __syncthreads();

  // ---- output: 2 rows x 32 cols x 64 ch ----
  int c=t&63, xg=t>>6;
  float mbr[16];
  #pragma unroll
  for(int s=0;s<16;s++) mbr[s]=smb[s*64+c];
  float bb=sbias[c];
  long ob0 = ((long)(b*128+2*gi)*128 + 2*gj0)*64;
  for(int k=0;k<16;k++){
    int o=xg+(k<<2);        // [0,64)
    int r=o>>5, xl=o&31;
    int hp=xl>>1, pos=((r&1)<<1)|(xl&1);
    const float4* h4=(const float4*)(she + hp*64 + pos*16);
    float4 h0=h4[0],h1=h4[1],h2=h4[2],h3=h4[3];
    float acc=bb;
    acc += h0.x*mbr[0]+h0.y*mbr[1]+h0.z*mbr[2]+h0.w*mbr[3];
    acc += h1.x*mbr[4]+h1.y*mbr[5]+h1.z*mbr[6]+h1.w*mbr[7];
    acc += h2.x*mbr[8]+h2.y*mbr[9]+h2.z*mbr[10]+h2.w*mbr[11];
    acc += h3.x*mbr[12]+h3.y*mbr[13]+h3.z*mbr[14]+h3.w*mbr[15];
    long oo = ob0 + (long)r*8192 + (long)xl*64 + c;
    if(bf) ((__hip_bfloat16*)out)[oo]=__float2bfloat16(acc);
    else   ((float*)out)[oo]=acc;
  }
}

extern "C" void kernel_launch(void* const* d_in, const int* in_sizes, int n_in,
                              void* d_out, int out_size, void* d_ws, size_t ws_size,
                              hipStream_t stream) {
  const void* x_in   = d_in[0];
  const void* Wq     = d_in[1];
  const void* Wk     = d_in[2];
  const void* Wv     = d_in[3];
  const void* Wr     = d_in[4];
  const void* We     = d_in[5];
  const void* qs_dw  = d_in[6];
  const void* qs_pw  = d_in[7];
  const void* qs_g   = d_in[8];
  const void* al_pw  = d_in[9];
  const void* al_dw  = d_in[10];
  const void* ah_pw  = d_in[11];
  const void* ah_dw  = d_in[12];
  const void* ph_pw  = d_in[13];
  const void* ph_s   = d_in[14];
  const void* bn_g   = d_in[15];
  const void* bn_b   = d_in[16];
  const void* mlp_in = d_in[17];
  const void* mlp_dw = d_in[18];
  const void* mlp_out= d_in[19];
  const void* res_s  = d_in[20];
  const void* rescale= d_in[21];
  const void* Wproj  = d_in[22];
  const void* bproj  = d_in[23];
  float* ws = (float*)d_ws;
  const int* flg = ((const int*)ws) + OFF_FLAG;

  float* FA = ws + OFF_S;
  float* FB = FA + FSZ;
  float* FC = FB + FSZ;
  float* FD = FC + FSZ;
  float* FE = FD + FSZ;
  float* M96 = FE + FSZ;            // 1.5M floats
  float* G96 = ws + OFF_QDIM;       // overlays dead qd/kd (dead after k_mix3)

  k_head<<<49,256,0,stream>>>(Wq,Wk,Wv,Wr,bn_g, ws);
  k_dims<<<512,256,0,stream>>>(x_in, ws, ws+OFF_QDIM, ws+OFF_KDIM, ws+OFF_VDIM, flg);
  // spatial(q) || fft_row(k) || wave_a(v)
  k_mix3<<<1024,256,0,stream>>>(ws+OFF_QDIM, ws+OFF_QMIX, qs_dw, qs_pw, qs_g,
                                ws+OFF_KDIM, FA, FB,
                                ws+OFF_VDIM, M96, mlp_in, bn_g, bn_b, flg);
  // col fft(k) || wave_dw chunk 0
  k_fft_col<<<2308,256,0,stream>>>(FA, FB, FC, FD, FE, al_pw, ah_pw, ph_pw, ph_s,
                                   M96, G96, mlp_dw, flg);
  k_four_dw<<<2080,256,0,stream>>>(FC, FD, FE, FA, FB, al_dw, ah_dw, flg);
  // inverse col fft(k) || wave_dw chunk 1
  k_ifft_col<<<2308,256,0,stream>>>(FA, FB, FC, FD, M96, G96, mlp_dw, flg);
  // ifft_row(k)+gram || wave_dw chunk 2
  k_irow_gram<<<2304,256,0,stream>>>(FC, FD, ws+OFF_QMIX, ws+OFF_G, M96, G96, mlp_dw, flg);
  k_attn<<<32,256,0,stream>>>(ws+OFF_G, ws+OFF_MB, We, Wproj, rescale, flg);
  k_epi2<<<1024,256,0,stream>>>(G96, ws+OFF_VDIM, ws+OFF_MB, mlp_out, res_s, bproj, d_out, flg);
}